// Round 3
// baseline (47.222 us; speedup 1.0000x reference)
//
#include <hip/hip_runtime.h>

// skipgram negative-sampling loss, MI355X.
// Row-PAIR per wave: lanes 0-31 serve row 2p, lanes 32-63 serve row 2p+1.
// Each lane loads float4 (16B) -> one VMEM instruction moves 1KB covering
// two rows (each half fully coalesced 512B). neg_score sums over K before
// logsigmoid -> elementwise-accumulate the 20 neg rows, one dot per row.
// 5-step half-wave butterfly + 1 cross-half shuffle; block reduce -> 2048 atomics.

constexpr int DIM  = 128;
constexpr int KNEG = 20;
constexpr int WAVES_PER_BLOCK = 4;

__device__ __forceinline__ float log_sigmoid(float x) {
    // stable: min(x,0) - log1p(exp(-|x|))
    return fminf(x, 0.0f) - log1pf(__expf(-fabsf(x)));
}

__global__ __launch_bounds__(256) void skipgram_kernel(
    const float* __restrict__ u_emb, const float* __restrict__ v_emb,
    const int* __restrict__ u_pos, const int* __restrict__ v_pos,
    const int* __restrict__ v_neg, float* __restrict__ out,
    int B, float neg_inv_b)
{
    const int lane  = threadIdx.x & 63;
    const int wslot = threadIdx.x >> 6;
    const int half  = lane >> 5;          // which row of the pair this lane serves
    const int l32   = lane & 31;          // lane within half-wave
    const int pair  = blockIdx.x * WAVES_PER_BLOCK + wslot;
    const int row   = pair * 2 + half;

    float contrib = 0.0f;

    if (row < B) {
        // ---- issue ALL loads for this half-wave's row up front ----
        const int up = u_pos[row];
        const int vp = v_pos[row];
        int idx[KNEG];
        #pragma unroll
        for (int k = 0; k < KNEG; ++k) idx[k] = v_neg[row * KNEG + k];

        const float4 uu = reinterpret_cast<const float4*>(u_emb + (size_t)up * DIM)[l32];
        const float4 vv = reinterpret_cast<const float4*>(v_emb + (size_t)vp * DIM)[l32];

        float4 nv[KNEG];
        #pragma unroll
        for (int k = 0; k < KNEG; ++k)
            nv[k] = reinterpret_cast<const float4*>(v_emb + (size_t)idx[k] * DIM)[l32];

        // ---- compute ----
        float pos = fmaf(uu.x, vv.x, fmaf(uu.y, vv.y, fmaf(uu.z, vv.z, uu.w * vv.w)));
        float ax = 0.0f, ay = 0.0f, az = 0.0f, aw = 0.0f;
        #pragma unroll
        for (int k = 0; k < KNEG; ++k) {
            ax += nv[k].x; ay += nv[k].y; az += nv[k].z; aw += nv[k].w;
        }
        float neg = fmaf(uu.x, ax, fmaf(uu.y, ay, fmaf(uu.z, az, uu.w * aw)));

        // 32-lane butterfly within each half-wave (halves stay independent)
        #pragma unroll
        for (int off = 16; off; off >>= 1) {
            pos += __shfl_xor(pos, off);
            neg += __shfl_xor(neg, off);
        }

        float loss = log_sigmoid(pos) + log_sigmoid(-neg);  // uniform within half
        contrib = (l32 == 0) ? loss : 0.0f;
    }

    // combine the two halves: lane 0 ends up with loss(row0)+loss(row1)
    contrib += __shfl_xor(contrib, 32);

    // ---- per-block reduction, one atomic per block ----
    __shared__ float wsum[WAVES_PER_BLOCK];
    if (lane == 0) wsum[wslot] = contrib;
    __syncthreads();
    if (threadIdx.x == 0) {
        float s = 0.0f;
        #pragma unroll
        for (int w = 0; w < WAVES_PER_BLOCK; ++w) s += wsum[w];
        atomicAdd(out, s * neg_inv_b);
    }
}

extern "C" void kernel_launch(void* const* d_in, const int* in_sizes, int n_in,
                              void* d_out, int out_size, void* d_ws, size_t ws_size,
                              hipStream_t stream) {
    const float* u_emb = (const float*)d_in[0];
    const float* v_emb = (const float*)d_in[1];
    const int*   u_pos = (const int*)d_in[2];
    const int*   v_pos = (const int*)d_in[3];
    const int*   v_neg = (const int*)d_in[4];
    float* out = (float*)d_out;

    const int B = in_sizes[2];            // 16384

    hipMemsetAsync(out, 0, sizeof(float), stream);

    const int pairs  = (B + 1) / 2;                               // 8192
    const int blocks = (pairs + WAVES_PER_BLOCK - 1) / WAVES_PER_BLOCK;  // 2048
    skipgram_kernel<<<blocks, WAVES_PER_BLOCK * 64, 0, stream>>>(
        u_emb, v_emb, u_pos, v_pos, v_neg, out, B, -1.0f / (float)B);
}

// Round 4
// 45.494 us; speedup vs baseline: 1.0380x; 1.0380x over previous
//
#include <hip/hip_runtime.h>

// skipgram negative-sampling loss, MI355X.
// Row-PAIR per wave: lanes 0-31 serve row 2p, lanes 32-63 serve row 2p+1.
// Each lane loads float4 (16B): one VMEM instruction moves 1KB covering two rows.
// All 22 gathers are forced to stay in flight via sched_barrier(0) between the
// load block and the accumulate block (compiler otherwise batches into 40 VGPRs
// and serializes ~5 latency rounds -> that was the round-3 bottleneck).
// neg_score sums over K before logsigmoid -> accumulate neg rows elementwise,
// one dot. Block reduce -> 2048 atomics.

constexpr int DIM  = 128;
constexpr int KNEG = 20;
constexpr int WAVES_PER_BLOCK = 4;

__device__ __forceinline__ float log_sigmoid(float x) {
    // stable: min(x,0) - log1p(exp(-|x|))
    return fminf(x, 0.0f) - log1pf(__expf(-fabsf(x)));
}

__global__ __launch_bounds__(256) void skipgram_kernel(
    const float* __restrict__ u_emb, const float* __restrict__ v_emb,
    const int* __restrict__ u_pos, const int* __restrict__ v_pos,
    const int* __restrict__ v_neg, float* __restrict__ out,
    int B, float neg_inv_b)
{
    const int lane  = threadIdx.x & 63;
    const int wslot = threadIdx.x >> 6;
    const int half  = lane >> 5;          // which row of the pair this lane serves
    const int l32   = lane & 31;          // lane within half-wave
    const int pair  = blockIdx.x * WAVES_PER_BLOCK + wslot;
    const int row   = pair * 2 + half;

    float contrib = 0.0f;

    if (row < B) {
        // ---- index loads (vectorized: 5 x int4 = 20 ints) ----
        const int up = u_pos[row];
        const int vp = v_pos[row];
        const int4* nidx4 = reinterpret_cast<const int4*>(v_neg + (size_t)row * KNEG);
        int4 iv[5];
        #pragma unroll
        for (int q = 0; q < 5; ++q) iv[q] = nidx4[q];
        int idx[KNEG];
        #pragma unroll
        for (int q = 0; q < 5; ++q) {
            idx[q * 4 + 0] = iv[q].x; idx[q * 4 + 1] = iv[q].y;
            idx[q * 4 + 2] = iv[q].z; idx[q * 4 + 3] = iv[q].w;
        }

        // ---- issue ALL 22 row gathers; keep them live past the barrier ----
        const float4 uu = reinterpret_cast<const float4*>(u_emb + (size_t)up * DIM)[l32];
        const float4 vv = reinterpret_cast<const float4*>(v_emb + (size_t)vp * DIM)[l32];
        float4 nv[KNEG];
        #pragma unroll
        for (int k = 0; k < KNEG; ++k)
            nv[k] = reinterpret_cast<const float4*>(v_emb + (size_t)idx[k] * DIM)[l32];

        __builtin_amdgcn_sched_barrier(0);   // loads above, math below

        // ---- compute ----
        float pos = fmaf(uu.x, vv.x, fmaf(uu.y, vv.y, fmaf(uu.z, vv.z, uu.w * vv.w)));
        float ax = 0.0f, ay = 0.0f, az = 0.0f, aw = 0.0f;
        #pragma unroll
        for (int k = 0; k < KNEG; ++k) {
            ax += nv[k].x; ay += nv[k].y; az += nv[k].z; aw += nv[k].w;
        }
        float neg = fmaf(uu.x, ax, fmaf(uu.y, ay, fmaf(uu.z, az, uu.w * aw)));

        // 32-lane butterfly within each half-wave (halves stay independent)
        #pragma unroll
        for (int off = 16; off; off >>= 1) {
            pos += __shfl_xor(pos, off);
            neg += __shfl_xor(neg, off);
        }

        float loss = log_sigmoid(pos) + log_sigmoid(-neg);  // uniform within half
        contrib = (l32 == 0) ? loss : 0.0f;
    }

    // combine the two halves: lane 0 ends up with loss(row0)+loss(row1)
    contrib += __shfl_xor(contrib, 32);

    // ---- per-block reduction, one atomic per block ----
    __shared__ float wsum[WAVES_PER_BLOCK];
    if (lane == 0) wsum[wslot] = contrib;
    __syncthreads();
    if (threadIdx.x == 0) {
        float s = 0.0f;
        #pragma unroll
        for (int w = 0; w < WAVES_PER_BLOCK; ++w) s += wsum[w];
        atomicAdd(out, s * neg_inv_b);
    }
}

extern "C" void kernel_launch(void* const* d_in, const int* in_sizes, int n_in,
                              void* d_out, int out_size, void* d_ws, size_t ws_size,
                              hipStream_t stream) {
    const float* u_emb = (const float*)d_in[0];
    const float* v_emb = (const float*)d_in[1];
    const int*   u_pos = (const int*)d_in[2];
    const int*   v_pos = (const int*)d_in[3];
    const int*   v_neg = (const int*)d_in[4];
    float* out = (float*)d_out;

    const int B = in_sizes[2];            // 16384

    hipMemsetAsync(out, 0, sizeof(float), stream);

    const int pairs  = (B + 1) / 2;                               // 8192
    const int blocks = (pairs + WAVES_PER_BLOCK - 1) / WAVES_PER_BLOCK;  // 2048
    skipgram_kernel<<<blocks, WAVES_PER_BLOCK * 64, 0, stream>>>(
        u_emb, v_emb, u_pos, v_pos, v_neg, out, B, -1.0f / (float)B);
}